// Round 9
// baseline (130.400 us; speedup 1.0000x reference)
//
#include <hip/hip_runtime.h>
#include <hip/hip_bf16.h>
#include <math.h>

#define NB 4
#define NC 512
#define NN 4096
#define NK 20
#define NCP 128
#define SPLIT 8
#define CHUNK (NN / SPLIT)   // 512 keys per split
#define NTILES (CHUNK / 64)  // 8

typedef __bf16 bf16x8 __attribute__((ext_vector_type(8)));
typedef float f32x4 __attribute__((ext_vector_type(4)));
typedef float f32x16 __attribute__((ext_vector_type(16)));
typedef short short8 __attribute__((ext_vector_type(8)));
typedef unsigned int uint4v __attribute__((ext_vector_type(4)));

static __device__ __forceinline__ unsigned short f2bf(float f) {
    unsigned int u = __builtin_bit_cast(unsigned int, f);
    unsigned int r = (u + 0x7FFFu + ((u >> 16) & 1u)) >> 16;
    return (unsigned short)r;
}
static __device__ __forceinline__ float bf2f(unsigned short h) {
    unsigned int u = ((unsigned int)h) << 16;
    return __builtin_bit_cast(float, u);
}
static __device__ __forceinline__ bf16x8 ldbf8(const unsigned short* p) {
    return __builtin_bit_cast(bf16x8, *reinterpret_cast<const short8*>(p));
}
static __device__ __forceinline__ void gld16(const unsigned short* g, unsigned short* l) {
    __builtin_amdgcn_global_load_lds(
        (const __attribute__((address_space(1))) unsigned int*)g,
        (__attribute__((address_space(3))) unsigned int*)l, 16, 0, 0);
}
static __device__ __forceinline__ unsigned int cvtpk(float lo, float hi) {
    unsigned int r;
    asm("v_cvt_pk_bf16_f32 %0, %1, %2" : "=v"(r) : "v"(lo), "v"(hi));
    return r;
}

#define MFMA16(a, b, c) __builtin_amdgcn_mfma_f32_16x16x32_bf16(a, b, c, 0, 0, 0)
#define MFMA32(a, b, c) __builtin_amdgcn_mfma_f32_32x32x16_bf16(a, b, c, 0, 0, 0)
#define SCHED0() __builtin_amdgcn_sched_barrier(0)
#define BAR() do { SCHED0(); __builtin_amdgcn_s_barrier(); SCHED0(); } while (0)

// ---------------- wconv: fp32 w -> bf16 wb ----------------
__global__ __launch_bounds__(256) void wconv_kernel(
    const float* __restrict__ w, unsigned short* __restrict__ wb)
{
    int i = blockIdx.x * 256 + threadIdx.x;   // 16384 float4s
    float4 v = reinterpret_cast<const float4*>(w)[i];
    unsigned int lo = (unsigned int)f2bf(v.x) | ((unsigned int)f2bf(v.y) << 16);
    unsigned int hi = (unsigned int)f2bf(v.z) | ((unsigned int)f2bf(v.w) << 16);
    reinterpret_cast<uint2*>(wb)[i] = make_uint2(lo, hi);
}

// ---------------- proj: fp[b][n][d] = sum_c feat[b][c][n]*w[d][c] + bias[d] ----
__global__ __launch_bounds__(256) void proj_kernel(
    const float* __restrict__ feat, const unsigned short* __restrict__ wb,
    const float* __restrict__ bias, unsigned short* __restrict__ fp,
    unsigned short* __restrict__ fpT)
{
    const int b = blockIdx.y;
    const int n0 = blockIdx.x * 64;
    const int tid = threadIdx.x;
    const int wid = tid >> 6;
    const int lane = tid & 63;
    const int lg = lane >> 4, lr = lane & 15;

    __shared__ unsigned short lds_f[2][64][40];   // dbuf [n][c] bf16, +8 pad

    const float* featb = feat + (size_t)b * NC * NN;

    f32x4 acc[2][4];
    #pragma unroll
    for (int i = 0; i < 2; ++i)
        #pragma unroll
        for (int j = 0; j < 4; ++j) acc[i][j] = (f32x4){0.f, 0.f, 0.f, 0.f};

    float4 pre[2];
    #pragma unroll
    for (int it = 0; it < 2; ++it) {
        int idx = it * 256 + tid;
        int cc = idx >> 4, q = idx & 15;
        pre[it] = *reinterpret_cast<const float4*>(&featb[(size_t)cc * NN + n0 + q * 4]);
    }

    for (int c0 = 0; c0 < NC; c0 += 32) {
        const int cur = (c0 >> 5) & 1;
        #pragma unroll
        for (int it = 0; it < 2; ++it) {
            int idx = it * 256 + tid;
            int cc = idx >> 4, q = idx & 15;
            float4 v = pre[it];
            lds_f[cur][q * 4 + 0][cc] = f2bf(v.x);
            lds_f[cur][q * 4 + 1][cc] = f2bf(v.y);
            lds_f[cur][q * 4 + 2][cc] = f2bf(v.z);
            lds_f[cur][q * 4 + 3][cc] = f2bf(v.w);
        }
        __syncthreads();
        if (c0 + 32 < NC) {
            #pragma unroll
            for (int it = 0; it < 2; ++it) {
                int idx = it * 256 + tid;
                int cc = idx >> 4, q = idx & 15;
                pre[it] = *reinterpret_cast<const float4*>(
                    &featb[(size_t)(c0 + 32 + cc) * NN + n0 + q * 4]);
            }
        }
        bf16x8 afr[2];
        #pragma unroll
        for (int dt = 0; dt < 2; ++dt)
            afr[dt] = ldbf8(&wb[(size_t)(wid * 32 + dt * 16 + lr) * NC + c0 + lg * 8]);
        #pragma unroll
        for (int n1 = 0; n1 < 4; ++n1) {
            bf16x8 bfr = ldbf8(&lds_f[cur][n1 * 16 + lr][lg * 8]);
            #pragma unroll
            for (int dt = 0; dt < 2; ++dt)
                acc[dt][n1] = MFMA16(afr[dt], bfr, acc[dt][n1]);
        }
    }
    #pragma unroll
    for (int dt = 0; dt < 2; ++dt)
        #pragma unroll
        for (int n1 = 0; n1 < 4; ++n1)
            #pragma unroll
            for (int i = 0; i < 4; ++i) {
                int d = wid * 32 + dt * 16 + lg * 4 + i;
                int n = n0 + n1 * 16 + lr;
                unsigned short h = f2bf(acc[dt][n1][i] + bias[d]);
                fp[((size_t)b * NN + n) * NCP + d] = h;
                fpT[((size_t)b * NCP + d) * NN + n] = h;
            }
}

// ---------------- class_term: ct[b][k][d] = sum_n cam[b][k][n]*fp[b][n][d] ----
__global__ __launch_bounds__(128) void ct_kernel(
    const float* __restrict__ cam, const unsigned short* __restrict__ fp,
    float* __restrict__ ct)
{
    const int bid = blockIdx.x;
    const int chunk = bid & 15;
    const int bk = bid >> 4;
    const int b = bk / NK, k = bk % NK;
    const int d2 = threadIdx.x & 63;
    const int half = threadIdx.x >> 6;
    const int nbase = chunk * 256 + half * 128;
    const float* camp = cam + ((size_t)b * NK + k) * NN + nbase;
    const unsigned short* fpp = fp + ((size_t)b * NN + nbase) * NCP + d2 * 2;
    float ax = 0.f, ay = 0.f;
    #pragma unroll 8
    for (int n = 0; n < 128; ++n) {
        float c = camp[n];
        unsigned int v = *reinterpret_cast<const unsigned int*>(&fpp[(size_t)n * NCP]);
        ax += c * bf2f((unsigned short)(v & 0xffff));
        ay += c * bf2f((unsigned short)(v >> 16));
    }
    float* ctp = &ct[((size_t)b * NK + k) * NCP + d2 * 2];
    atomicAdd(ctp, ax);
    atomicAdd(ctp + 1, ay);
}

// ---------------- attention partials over a 512-key chunk ----------------
// 512 threads = 8 waves; wave owns 32 q (block = 256 q); 32x32x16 MFMA.
// K+V double-buffered (64 KB); ONE barrier pair per tile.
// 1D grid 512, XCD-pinned decode: all 16 blocks of a (sidx,b) KV group land
// on the same XCD -> group's 256 KB KV stays resident in that XCD's L2.
__global__ __launch_bounds__(512, 4) void attn_partial_kernel(
    const unsigned short* __restrict__ fp, const unsigned short* __restrict__ fpT,
    unsigned short* __restrict__ po, float* __restrict__ mbuf, float* __restrict__ lbuf)
{
    const int id = blockIdx.x;
    const int xcd = id & 7;
    const int j = id >> 3;
    const int group = xcd + ((j >> 4) << 3);   // 0..31, constant per XCD
    const int xq = j & 15;
    const int sidx = group & 7;
    const int b = group >> 3;

    const int tid = threadIdx.x;
    const int wid = tid >> 6;
    const int lane = tid & 63;
    const int l31 = lane & 31, hi = lane >> 5;
    const int q0 = xq * 256 + wid * 32;
    const int kvbase = sidx * CHUNK;

    __shared__ unsigned short kt[2][64 * 128];   // K dbuf: [kv][d], 16-chunk XOR (rk&15)
    __shared__ unsigned short vt[2][64 * 128];   // V dbuf: pair-rows [d>>1][256B], XOR (rowp&15)

    const unsigned short* fpb  = fp  + (size_t)b * NN * NCP;
    const unsigned short* fpTb = fpT + (size_t)b * NCP * NN;

    // staging offsets: 2 K chunks + 2 V chunks per thread (1024 x 16B each tile)
    int offK[2], offV[2];
    #pragma unroll
    for (int i = 0; i < 2; ++i) {
        int oc = i * 512 + tid;
        int rk = oc >> 4, ck = oc & 15;
        offK[i] = rk * NCP + ((ck ^ (rk & 15)) << 3);
        int rowp = oc >> 4, cv = oc & 15;
        int cg = cv ^ (rowp & 15);
        int d = rowp * 2 + (cg >> 3), kvc = cg & 7;
        offV[i] = d * NN + (kvc << 3);
    }

    // Q fragments (B operand): col q = l31, depth d = kk*16 + hi*8 + j
    bf16x8 qf[8];
    #pragma unroll
    for (int kk = 0; kk < 8; ++kk)
        qf[kk] = ldbf8(&fpb[(size_t)(q0 + l31) * NCP + kk * 16 + hi * 8]);

    f32x16 o[4];
    #pragma unroll
    for (int dt = 0; dt < 4; ++dt)
        #pragma unroll
        for (int jj = 0; jj < 16; ++jj) o[dt][jj] = 0.f;
    float m_i = -INFINITY, l_i = 0.f;

    // prologue: stage K[0], V[0]
    {
        const unsigned short* k0 = fpb + (size_t)kvbase * NCP;
        const unsigned short* v0 = fpTb + kvbase;
        #pragma unroll
        for (int i = 0; i < 2; ++i) {
            gld16(k0 + offK[i], &kt[0][(i * 512 + wid * 64) * 8]);
            gld16(v0 + offV[i], &vt[0][(i * 512 + wid * 64) * 8]);
        }
    }
    SCHED0();
    asm volatile("s_waitcnt vmcnt(0)" ::: "memory");
    BAR();

    for (int t = 0; t < NTILES; ++t) {
        const int cur = t & 1;
        // ---- issue next-tile K/V stages into the other buffers ----
        if (t + 1 < NTILES) {
            const int tn = t + 1;
            const unsigned short* knext = fpb + (size_t)(kvbase + tn * 64) * NCP;
            const unsigned short* vnext = fpTb + kvbase + tn * 64;
            #pragma unroll
            for (int i = 0; i < 2; ++i) {
                gld16(knext + offK[i], &kt[cur ^ 1][(i * 512 + wid * 64) * 8]);
                gld16(vnext + offV[i], &vt[cur ^ 1][(i * 512 + wid * 64) * 8]);
            }
        }
        SCHED0();
        // ---- S^T = K Q^T ----
        const unsigned short* ktc = &kt[cur][0];
        f32x16 s[2];
        #pragma unroll
        for (int g = 0; g < 2; ++g)
            #pragma unroll
            for (int jj = 0; jj < 16; ++jj) s[g][jj] = 0.f;
        __builtin_amdgcn_s_setprio(1);
        #pragma unroll
        for (int kk = 0; kk < 8; ++kk) {
            #pragma unroll
            for (int g = 0; g < 2; ++g) {
                int row = g * 32 + l31;
                bf16x8 kf = ldbf8(&ktc[row * 128 + (((kk * 2 + hi) ^ (row & 15)) << 3)]);
                s[g] = MFMA32(kf, qf[kk], s[g]);
            }
        }
        __builtin_amdgcn_s_setprio(0);
        // ---- online softmax: lane owns q = l31 ----
        float pmax = s[0][0];
        #pragma unroll
        for (int g = 0; g < 2; ++g)
            #pragma unroll
            for (int jj = 0; jj < 16; ++jj) pmax = fmaxf(pmax, s[g][jj]);
        pmax = fmaxf(pmax, __shfl_xor(pmax, 32));
        if (!__all(pmax - m_i <= 8.f)) {   // defer-max (THR=8)
            float mnew = fmaxf(m_i, pmax);
            float sc = __expf(m_i - mnew);
            l_i *= sc;
            #pragma unroll
            for (int dt = 0; dt < 4; ++dt)
                #pragma unroll
                for (int jj = 0; jj < 16; ++jj) o[dt][jj] *= sc;
            m_i = mnew;
        }
        float sum = 0.f;
        #pragma unroll
        for (int g = 0; g < 2; ++g)
            #pragma unroll
            for (int jj = 0; jj < 16; ++jj) {
                float e = __expf(s[g][jj] - m_i);
                s[g][jj] = e;
                sum += e;
            }
        sum += __shfl_xor(sum, 32);
        l_i += sum;
        // ---- P^T -> bf16 words -> register exchange (8 permlane32_swap) ----
        unsigned int wk[2][8];
        #pragma unroll
        for (int g = 0; g < 2; ++g)
            #pragma unroll
            for (int m = 0; m < 8; ++m)
                wk[g][m] = cvtpk(s[g][2 * m], s[g][2 * m + 1]);
        bf16x8 pf[4];
        #pragma unroll
        for (int g = 0; g < 2; ++g)
            #pragma unroll
            for (int sub = 0; sub < 2; ++sub) {
                unsigned int A0 = wk[g][4 * sub],     B0 = wk[g][4 * sub + 2];
                unsigned int A1 = wk[g][4 * sub + 1], B1 = wk[g][4 * sub + 3];
                asm("v_permlane32_swap_b32 %0, %1" : "+v"(A0), "+v"(B0));
                asm("v_permlane32_swap_b32 %0, %1" : "+v"(A1), "+v"(B1));
                uint4v u;
                u[0] = A0; u[1] = A1; u[2] = B0; u[3] = B1;
                pf[2 * g + sub] = __builtin_bit_cast(bf16x8, u);
            }
        // ---- O^T += V^T P^T from vt[cur] ----
        const unsigned short* vtc = &vt[cur][0];
        __builtin_amdgcn_s_setprio(1);
        #pragma unroll
        for (int c2 = 0; c2 < 4; ++c2) {
            #pragma unroll
            for (int dt = 0; dt < 4; ++dt) {
                int row32 = dt * 32 + l31;
                int rowp = row32 >> 1;
                int chunk = (row32 & 1) * 8 + c2 * 2 + hi;
                bf16x8 vf = ldbf8(&vtc[rowp * 128 + ((chunk ^ (rowp & 15)) << 3)]);
                o[dt] = MFMA32(vf, pf[c2], o[dt]);
            }
        }
        __builtin_amdgcn_s_setprio(0);
        SCHED0();
        asm volatile("s_waitcnt vmcnt(0)" ::: "memory");  // next K,V landed
        BAR();
    }
    // write unnormalized partials (bf16): d = dt*32 + qd*8 + 4*hi + {0..3}
    const size_t pbase = (size_t)(b * SPLIT + sidx) * NN + q0;
    const size_t rowoff = (pbase + l31) * NCP;
    #pragma unroll
    for (int dt = 0; dt < 4; ++dt)
        #pragma unroll
        for (int qd = 0; qd < 4; ++qd) {
            unsigned int u0 = cvtpk(o[dt][qd * 4 + 0], o[dt][qd * 4 + 1]);
            unsigned int u1 = cvtpk(o[dt][qd * 4 + 2], o[dt][qd * 4 + 3]);
            *reinterpret_cast<uint2*>(&po[rowoff + dt * 32 + qd * 8 + hi * 4]) =
                make_uint2(u0, u1);
        }
    if (hi == 0) {
        mbuf[pbase + l31] = m_i;
        lbuf[pbase + l31] = l_i;
    }
}

// ---------------- merge partials -> pt (bf16) ----------------
__global__ __launch_bounds__(256) void merge_kernel(
    const unsigned short* __restrict__ po, const float* __restrict__ mbuf,
    const float* __restrict__ lbuf, unsigned short* __restrict__ pt)
{
    const int b = blockIdx.y;
    const int n = blockIdx.x * 4 + (threadIdx.x >> 6);
    const int lane = threadIdx.x & 63;
    float m_s[SPLIT], l_s[SPLIT];
    float M = -INFINITY;
    #pragma unroll
    for (int s = 0; s < SPLIT; ++s) {
        m_s[s] = mbuf[(size_t)(b * SPLIT + s) * NN + n];
        l_s[s] = lbuf[(size_t)(b * SPLIT + s) * NN + n];
        M = fmaxf(M, m_s[s]);
    }
    float L = 0.f, wgt[SPLIT];
    #pragma unroll
    for (int s = 0; s < SPLIT; ++s) { wgt[s] = __expf(m_s[s] - M); L += wgt[s] * l_s[s]; }
    const float inv = 1.f / L;
    float ax = 0.f, ay = 0.f;
    #pragma unroll
    for (int s = 0; s < SPLIT; ++s) {
        unsigned int v = *reinterpret_cast<const unsigned int*>(
            &po[((size_t)(b * SPLIT + s) * NN + n) * NCP + lane * 2]);
        ax += wgt[s] * bf2f((unsigned short)(v & 0xffff));
        ay += wgt[s] * bf2f((unsigned short)(v >> 16));
    }
    unsigned int outw = (unsigned int)f2bf(ax * inv) | ((unsigned int)f2bf(ay * inv) << 16);
    *reinterpret_cast<unsigned int*>(&pt[((size_t)b * NN + n) * NCP + lane * 2]) = outw;
}

// ---------------- aug via MFMA: out[b][k][n] = cam + sum_d ct[b][k][d]*pt[b][n][d] ----
__global__ __launch_bounds__(256) void aug_kernel(
    const float* __restrict__ cam, const float* __restrict__ ct,
    const unsigned short* __restrict__ pt, float* __restrict__ out)
{
    const int b = blockIdx.y;
    const int tid = threadIdx.x, wid = tid >> 6, lane = tid & 63;
    const int lg = lane >> 4, lr = lane & 15;
    const int n0 = blockIdx.x * 64 + wid * 16;
    const unsigned short* ptb = pt + (size_t)b * NN * NCP;
    const float* ctb = ct + (size_t)b * NK * NCP;

    f32x4 acc[2];
    acc[0] = (f32x4){0.f, 0.f, 0.f, 0.f};
    acc[1] = (f32x4){0.f, 0.f, 0.f, 0.f};
    #pragma unroll
    for (int kk = 0; kk < 4; ++kk) {
        bf16x8 af = ldbf8(&ptb[(size_t)(n0 + lr) * NCP + kk * 32 + lg * 8]);
        #pragma unroll
        for (int c = 0; c < 2; ++c) {
            int k = c * 16 + lr;
            short8 bv;
            if (k < NK) {
                const float* cr = &ctb[(size_t)k * NCP + kk * 32 + lg * 8];
                #pragma unroll
                for (int j = 0; j < 8; ++j) bv[j] = (short)f2bf(cr[j]);
            } else {
                #pragma unroll
                for (int j = 0; j < 8; ++j) bv[j] = 0;
            }
            acc[c] = MFMA16(af, __builtin_bit_cast(bf16x8, bv), acc[c]);
        }
    }
    #pragma unroll
    for (int c = 0; c < 2; ++c) {
        int k = c * 16 + lr;
        if (k < NK) {
            #pragma unroll
            for (int i = 0; i < 4; ++i) {
                size_t off = ((size_t)b * NK + k) * NN + n0 + lg * 4 + i;
                out[off] = cam[off] + acc[c][i];
            }
        }
    }
}

extern "C" void kernel_launch(void* const* d_in, const int* in_sizes, int n_in,
                              void* d_out, int out_size, void* d_ws, size_t ws_size,
                              hipStream_t stream) {
    const float* feat = (const float*)d_in[0];
    const float* cam  = (const float*)d_in[1];
    const float* wpr  = (const float*)d_in[2];
    const float* bpr  = (const float*)d_in[3];
    float* out = (float*)d_out;

    const size_t MB = 1024 * 1024;
    char* ws = (char*)d_ws;
    unsigned short* fp  = (unsigned short*)(ws);                 // 4 MB
    unsigned short* fpT = (unsigned short*)(ws + 4 * MB);        // 4 MB
    unsigned short* pt  = (unsigned short*)(ws + 8 * MB);        // 4 MB
    float* ct           = (float*)(ws + 12 * MB);                // 40 KB
    unsigned short* wb  = (unsigned short*)(ws + 12 * MB + 512 * 1024); // 128 KB
    unsigned short* po  = (unsigned short*)(ws + 13 * MB);       // 32 MB bf16 partial O
    float* mbuf         = (float*)(ws + 45 * MB);                // 512 KB
    float* lbuf         = (float*)(ws + 46 * MB);                // 512 KB

    hipMemsetAsync(ct, 0, (size_t)NB * NK * NCP * sizeof(float), stream);
    wconv_kernel<<<64, 256, 0, stream>>>(wpr, wb);
    proj_kernel<<<dim3(NN / 64, NB), 256, 0, stream>>>(feat, wb, bpr, fp, fpT);
    ct_kernel<<<NB * NK * 16, 128, 0, stream>>>(cam, fp, ct);
    attn_partial_kernel<<<512, 512, 0, stream>>>(fp, fpT, po, mbuf, lbuf);
    merge_kernel<<<dim3(NN / 4, NB), 256, 0, stream>>>(po, mbuf, lbuf, pt);
    aug_kernel<<<dim3(NN / 64, NB), 256, 0, stream>>>(cam, ct, pt, out);
}

// Round 10
// 95.228 us; speedup vs baseline: 1.3693x; 1.3693x over previous
//
#include <hip/hip_runtime.h>
#include <hip/hip_bf16.h>
#include <math.h>

#define NB 4
#define NC 512
#define NN 4096
#define NK 20
#define NCP 128
#define SPLIT 4
#define CHUNK (NN / SPLIT)   // 1024 keys per split
#define NTILES (CHUNK / 64)  // 16

typedef __bf16 bf16x8 __attribute__((ext_vector_type(8)));
typedef float f32x4 __attribute__((ext_vector_type(4)));
typedef float f32x16 __attribute__((ext_vector_type(16)));
typedef short short8 __attribute__((ext_vector_type(8)));
typedef unsigned int uint4v __attribute__((ext_vector_type(4)));

static __device__ __forceinline__ unsigned short f2bf(float f) {
    unsigned int u = __builtin_bit_cast(unsigned int, f);
    unsigned int r = (u + 0x7FFFu + ((u >> 16) & 1u)) >> 16;
    return (unsigned short)r;
}
static __device__ __forceinline__ float bf2f(unsigned short h) {
    unsigned int u = ((unsigned int)h) << 16;
    return __builtin_bit_cast(float, u);
}
static __device__ __forceinline__ bf16x8 ldbf8(const unsigned short* p) {
    return __builtin_bit_cast(bf16x8, *reinterpret_cast<const short8*>(p));
}
static __device__ __forceinline__ void gld16(const unsigned short* g, unsigned short* l) {
    __builtin_amdgcn_global_load_lds(
        (const __attribute__((address_space(1))) unsigned int*)g,
        (__attribute__((address_space(3))) unsigned int*)l, 16, 0, 0);
}
static __device__ __forceinline__ unsigned int cvtpk(float lo, float hi) {
    unsigned int r;
    asm("v_cvt_pk_bf16_f32 %0, %1, %2" : "=v"(r) : "v"(lo), "v"(hi));
    return r;
}

#define MFMA16(a, b, c) __builtin_amdgcn_mfma_f32_16x16x32_bf16(a, b, c, 0, 0, 0)
#define MFMA32(a, b, c) __builtin_amdgcn_mfma_f32_32x32x16_bf16(a, b, c, 0, 0, 0)
#define SCHED0() __builtin_amdgcn_sched_barrier(0)
#define BAR() do { SCHED0(); __builtin_amdgcn_s_barrier(); SCHED0(); } while (0)

// ---------------- wconv: fp32 w -> bf16 wb ----------------
__global__ __launch_bounds__(256) void wconv_kernel(
    const float* __restrict__ w, unsigned short* __restrict__ wb)
{
    int i = blockIdx.x * 256 + threadIdx.x;   // 16384 float4s
    float4 v = reinterpret_cast<const float4*>(w)[i];
    unsigned int lo = (unsigned int)f2bf(v.x) | ((unsigned int)f2bf(v.y) << 16);
    unsigned int hi = (unsigned int)f2bf(v.z) | ((unsigned int)f2bf(v.w) << 16);
    reinterpret_cast<uint2*>(wb)[i] = make_uint2(lo, hi);
}

// ---------------- proj: fp[b][n][d] = sum_c feat[b][c][n]*w[d][c] + bias[d] ----
__global__ __launch_bounds__(256) void proj_kernel(
    const float* __restrict__ feat, const unsigned short* __restrict__ wb,
    const float* __restrict__ bias, unsigned short* __restrict__ fp,
    unsigned short* __restrict__ fpT)
{
    const int b = blockIdx.y;
    const int n0 = blockIdx.x * 64;
    const int tid = threadIdx.x;
    const int wid = tid >> 6;
    const int lane = tid & 63;
    const int lg = lane >> 4, lr = lane & 15;

    __shared__ unsigned short lds_f[2][64][40];   // dbuf [n][c] bf16, +8 pad

    const float* featb = feat + (size_t)b * NC * NN;

    f32x4 acc[2][4];
    #pragma unroll
    for (int i = 0; i < 2; ++i)
        #pragma unroll
        for (int j = 0; j < 4; ++j) acc[i][j] = (f32x4){0.f, 0.f, 0.f, 0.f};

    float4 pre[2];
    #pragma unroll
    for (int it = 0; it < 2; ++it) {
        int idx = it * 256 + tid;
        int cc = idx >> 4, q = idx & 15;
        pre[it] = *reinterpret_cast<const float4*>(&featb[(size_t)cc * NN + n0 + q * 4]);
    }

    for (int c0 = 0; c0 < NC; c0 += 32) {
        const int cur = (c0 >> 5) & 1;
        #pragma unroll
        for (int it = 0; it < 2; ++it) {
            int idx = it * 256 + tid;
            int cc = idx >> 4, q = idx & 15;
            float4 v = pre[it];
            lds_f[cur][q * 4 + 0][cc] = f2bf(v.x);
            lds_f[cur][q * 4 + 1][cc] = f2bf(v.y);
            lds_f[cur][q * 4 + 2][cc] = f2bf(v.z);
            lds_f[cur][q * 4 + 3][cc] = f2bf(v.w);
        }
        __syncthreads();
        if (c0 + 32 < NC) {
            #pragma unroll
            for (int it = 0; it < 2; ++it) {
                int idx = it * 256 + tid;
                int cc = idx >> 4, q = idx & 15;
                pre[it] = *reinterpret_cast<const float4*>(
                    &featb[(size_t)(c0 + 32 + cc) * NN + n0 + q * 4]);
            }
        }
        bf16x8 afr[2];
        #pragma unroll
        for (int dt = 0; dt < 2; ++dt)
            afr[dt] = ldbf8(&wb[(size_t)(wid * 32 + dt * 16 + lr) * NC + c0 + lg * 8]);
        #pragma unroll
        for (int n1 = 0; n1 < 4; ++n1) {
            bf16x8 bfr = ldbf8(&lds_f[cur][n1 * 16 + lr][lg * 8]);
            #pragma unroll
            for (int dt = 0; dt < 2; ++dt)
                acc[dt][n1] = MFMA16(afr[dt], bfr, acc[dt][n1]);
        }
    }
    #pragma unroll
    for (int dt = 0; dt < 2; ++dt)
        #pragma unroll
        for (int n1 = 0; n1 < 4; ++n1)
            #pragma unroll
            for (int i = 0; i < 4; ++i) {
                int d = wid * 32 + dt * 16 + lg * 4 + i;
                int n = n0 + n1 * 16 + lr;
                unsigned short h = f2bf(acc[dt][n1][i] + bias[d]);
                fp[((size_t)b * NN + n) * NCP + d] = h;
                fpT[((size_t)b * NCP + d) * NN + n] = h;
            }
}

// ---------------- class_term: ct[b][k][d] = sum_n cam[b][k][n]*fp[b][n][d] ----
__global__ __launch_bounds__(128) void ct_kernel(
    const float* __restrict__ cam, const unsigned short* __restrict__ fp,
    float* __restrict__ ct)
{
    const int bid = blockIdx.x;
    const int chunk = bid & 15;
    const int bk = bid >> 4;
    const int b = bk / NK, k = bk % NK;
    const int d2 = threadIdx.x & 63;
    const int half = threadIdx.x >> 6;
    const int nbase = chunk * 256 + half * 128;
    const float* camp = cam + ((size_t)b * NK + k) * NN + nbase;
    const unsigned short* fpp = fp + ((size_t)b * NN + nbase) * NCP + d2 * 2;
    float ax = 0.f, ay = 0.f;
    #pragma unroll 8
    for (int n = 0; n < 128; ++n) {
        float c = camp[n];
        unsigned int v = *reinterpret_cast<const unsigned int*>(&fpp[(size_t)n * NCP]);
        ax += c * bf2f((unsigned short)(v & 0xffff));
        ay += c * bf2f((unsigned short)(v >> 16));
    }
    float* ctp = &ct[((size_t)b * NK + k) * NCP + d2 * 2];
    atomicAdd(ctp, ax);
    atomicAdd(ctp + 1, ay);
}

// ---------------- attention partials over a 1024-key chunk ----------------
// 256 threads = 4 waves; wave owns 32 q; 32x32x16 MFMA; SPLIT=4, 16 tiles.
// LDS 48 KB: K dbuf + V single -> 3 blocks/CU; grid 512 -> all resident, no tail.
// Tile: issue V[t]+K[t+1] -> QK^T -> softmax -> exchange -> vmcnt(4) bar
//       -> PV -> vmcnt(0) bar.
__global__ __launch_bounds__(256, 3) void attn_partial_kernel(
    const unsigned short* __restrict__ fp, const unsigned short* __restrict__ fpT,
    unsigned short* __restrict__ po, float* __restrict__ mbuf, float* __restrict__ lbuf)
{
    const int b = blockIdx.z;
    const int sidx = blockIdx.y;
    const int tid = threadIdx.x;
    const int wid = tid >> 6;
    const int lane = tid & 63;
    const int l31 = lane & 31, hi = lane >> 5;
    const int q0 = blockIdx.x * 128 + wid * 32;
    const int kvbase = sidx * CHUNK;

    __shared__ unsigned short kt[2][64 * 128];   // K dbuf: [kv][d], 16-chunk XOR (rk&15)
    __shared__ unsigned short vt[64 * 128];      // V single: pair-rows [d>>1][256B], XOR

    const unsigned short* fpb  = fp  + (size_t)b * NN * NCP;
    const unsigned short* fpTb = fpT + (size_t)b * NCP * NN;

    // staging offsets: 4 K chunks + 4 V chunks per thread (1024 x 16B each tile)
    int offK[4], offV[4];
    #pragma unroll
    for (int i = 0; i < 4; ++i) {
        int oc = i * 256 + tid;
        int rk = oc >> 4, ck = oc & 15;
        offK[i] = rk * NCP + ((ck ^ (rk & 15)) << 3);
        int rowp = oc >> 4, cv = oc & 15;
        int cg = cv ^ (rowp & 15);
        int d = rowp * 2 + (cg >> 3), kvc = cg & 7;
        offV[i] = d * NN + (kvc << 3);
    }

    // Q fragments (B operand): col q = l31, depth d = kk*16 + hi*8 + j
    bf16x8 qf[8];
    #pragma unroll
    for (int kk = 0; kk < 8; ++kk)
        qf[kk] = ldbf8(&fpb[(size_t)(q0 + l31) * NCP + kk * 16 + hi * 8]);

    f32x16 o[4];
    #pragma unroll
    for (int dt = 0; dt < 4; ++dt)
        #pragma unroll
        for (int j = 0; j < 16; ++j) o[dt][j] = 0.f;
    float m_i = -INFINITY, l_i = 0.f;

    // prologue: stage K[0]
    {
        const unsigned short* k0 = fpb + (size_t)kvbase * NCP;
        #pragma unroll
        for (int i = 0; i < 4; ++i)
            gld16(k0 + offK[i], &kt[0][(i * 256 + wid * 64) * 8]);
    }
    SCHED0();
    asm volatile("s_waitcnt vmcnt(0)" ::: "memory");
    BAR();

    for (int t = 0; t < NTILES; ++t) {
        const int cur = t & 1;
        // ---- issue V[t] (4 loads) then K[t+1] (4 loads, wraparound) ----
        {
            const unsigned short* vnow = fpTb + kvbase + t * 64;
            #pragma unroll
            for (int i = 0; i < 4; ++i)
                gld16(vnow + offV[i], &vt[(i * 256 + wid * 64) * 8]);
            const int tn = (t + 1) & (NTILES - 1);
            const unsigned short* knext = fpb + (size_t)(kvbase + tn * 64) * NCP;
            #pragma unroll
            for (int i = 0; i < 4; ++i)
                gld16(knext + offK[i], &kt[cur ^ 1][(i * 256 + wid * 64) * 8]);
        }
        SCHED0();
        // ---- S^T = K Q^T ----
        const unsigned short* ktc = &kt[cur][0];
        f32x16 s[2];
        #pragma unroll
        for (int g = 0; g < 2; ++g)
            #pragma unroll
            for (int j = 0; j < 16; ++j) s[g][j] = 0.f;
        __builtin_amdgcn_s_setprio(1);
        #pragma unroll
        for (int kk = 0; kk < 8; ++kk) {
            #pragma unroll
            for (int g = 0; g < 2; ++g) {
                int row = g * 32 + l31;
                bf16x8 kf = ldbf8(&ktc[row * 128 + (((kk * 2 + hi) ^ (row & 15)) << 3)]);
                s[g] = MFMA32(kf, qf[kk], s[g]);
            }
        }
        __builtin_amdgcn_s_setprio(0);
        // ---- online softmax: lane owns q = l31 ----
        float pmax = s[0][0];
        #pragma unroll
        for (int g = 0; g < 2; ++g)
            #pragma unroll
            for (int j = 0; j < 16; ++j) pmax = fmaxf(pmax, s[g][j]);
        pmax = fmaxf(pmax, __shfl_xor(pmax, 32));
        if (!__all(pmax - m_i <= 8.f)) {   // defer-max (THR=8)
            float mnew = fmaxf(m_i, pmax);
            float sc = __expf(m_i - mnew);
            l_i *= sc;
            #pragma unroll
            for (int dt = 0; dt < 4; ++dt)
                #pragma unroll
                for (int j = 0; j < 16; ++j) o[dt][j] *= sc;
            m_i = mnew;
        }
        float sum = 0.f;
        #pragma unroll
        for (int g = 0; g < 2; ++g)
            #pragma unroll
            for (int j = 0; j < 16; ++j) {
                float e = __expf(s[g][j] - m_i);
                s[g][j] = e;
                sum += e;
            }
        sum += __shfl_xor(sum, 32);
        l_i += sum;
        // ---- P^T -> bf16 words -> register exchange (8 permlane32_swap) ----
        unsigned int wk[2][8];
        #pragma unroll
        for (int g = 0; g < 2; ++g)
            #pragma unroll
            for (int m = 0; m < 8; ++m)
                wk[g][m] = cvtpk(s[g][2 * m], s[g][2 * m + 1]);
        bf16x8 pf[4];
        #pragma unroll
        for (int g = 0; g < 2; ++g)
            #pragma unroll
            for (int sub = 0; sub < 2; ++sub) {
                unsigned int A0 = wk[g][4 * sub],     B0 = wk[g][4 * sub + 2];
                unsigned int A1 = wk[g][4 * sub + 1], B1 = wk[g][4 * sub + 3];
                asm("v_permlane32_swap_b32 %0, %1" : "+v"(A0), "+v"(B0));
                asm("v_permlane32_swap_b32 %0, %1" : "+v"(A1), "+v"(B1));
                uint4v u;
                u[0] = A0; u[1] = A1; u[2] = B0; u[3] = B1;
                pf[2 * g + sub] = __builtin_bit_cast(bf16x8, u);
            }
        SCHED0();
        asm volatile("s_waitcnt vmcnt(4)" ::: "memory");  // V landed, K in flight
        BAR();
        // ---- O^T += V^T P^T ----
        __builtin_amdgcn_s_setprio(1);
        #pragma unroll
        for (int c2 = 0; c2 < 4; ++c2) {
            #pragma unroll
            for (int dt = 0; dt < 4; ++dt) {
                int row32 = dt * 32 + l31;
                int rowp = row32 >> 1;
                int chunk = (row32 & 1) * 8 + c2 * 2 + hi;
                bf16x8 vf = ldbf8(&vt[rowp * 128 + ((chunk ^ (rowp & 15)) << 3)]);
                o[dt] = MFMA32(vf, pf[c2], o[dt]);
            }
        }
        __builtin_amdgcn_s_setprio(0);
        SCHED0();
        asm volatile("s_waitcnt vmcnt(0)" ::: "memory");  // K[t+1] landed
        BAR();
    }
    // write unnormalized partials (bf16): d = dt*32 + qd*8 + 4*hi + {0..3}
    const size_t pbase = (size_t)(b * SPLIT + sidx) * NN + q0;
    const size_t rowoff = (pbase + l31) * NCP;
    #pragma unroll
    for (int dt = 0; dt < 4; ++dt)
        #pragma unroll
        for (int qd = 0; qd < 4; ++qd) {
            unsigned int u0 = cvtpk(o[dt][qd * 4 + 0], o[dt][qd * 4 + 1]);
            unsigned int u1 = cvtpk(o[dt][qd * 4 + 2], o[dt][qd * 4 + 3]);
            *reinterpret_cast<uint2*>(&po[rowoff + dt * 32 + qd * 8 + hi * 4]) =
                make_uint2(u0, u1);
        }
    if (hi == 0) {
        mbuf[pbase + l31] = m_i;
        lbuf[pbase + l31] = l_i;
    }
}

// ---------------- aug (merge fused): out = cam + ct . merge(po)^T ----------------
// Each thread merges its own A-fragment elements from the 4 split partials in
// registers (no LDS, no extra sync), then the MFMA epilogue as before.
__global__ __launch_bounds__(256) void aug_kernel(
    const float* __restrict__ cam, const float* __restrict__ ct,
    const unsigned short* __restrict__ po, const float* __restrict__ mbuf,
    const float* __restrict__ lbuf, float* __restrict__ out)
{
    const int b = blockIdx.y;
    const int tid = threadIdx.x, wid = tid >> 6, lane = tid & 63;
    const int lg = lane >> 4, lr = lane & 15;
    const int n0 = blockIdx.x * 64 + wid * 16;
    const int row = n0 + lr;
    const float* ctb = ct + (size_t)b * NK * NCP;

    // merge weights for this row
    float m_s[SPLIT], l_s[SPLIT], M = -INFINITY;
    #pragma unroll
    for (int s = 0; s < SPLIT; ++s) {
        m_s[s] = mbuf[(size_t)(b * SPLIT + s) * NN + row];
        l_s[s] = lbuf[(size_t)(b * SPLIT + s) * NN + row];
        M = fmaxf(M, m_s[s]);
    }
    float L = 0.f, wgt[SPLIT];
    #pragma unroll
    for (int s = 0; s < SPLIT; ++s) { wgt[s] = __expf(m_s[s] - M); L += wgt[s] * l_s[s]; }
    const float inv = 1.f / L;
    #pragma unroll
    for (int s = 0; s < SPLIT; ++s) wgt[s] *= inv;

    f32x4 acc[2];
    acc[0] = (f32x4){0.f, 0.f, 0.f, 0.f};
    acc[1] = (f32x4){0.f, 0.f, 0.f, 0.f};
    #pragma unroll
    for (int kk = 0; kk < 4; ++kk) {
        // merged A fragment: pt[row][kk*32 + lg*8 .. +8]
        float mg[8];
        #pragma unroll
        for (int j = 0; j < 8; ++j) mg[j] = 0.f;
        #pragma unroll
        for (int s = 0; s < SPLIT; ++s) {
            uint4v v = *reinterpret_cast<const uint4v*>(
                &po[((size_t)(b * SPLIT + s) * NN + row) * NCP + kk * 32 + lg * 8]);
            #pragma unroll
            for (int j = 0; j < 4; ++j) {
                mg[2 * j]     += wgt[s] * bf2f((unsigned short)(v[j] & 0xffff));
                mg[2 * j + 1] += wgt[s] * bf2f((unsigned short)(v[j] >> 16));
            }
        }
        uint4v au;
        #pragma unroll
        for (int j = 0; j < 4; ++j) au[j] = cvtpk(mg[2 * j], mg[2 * j + 1]);
        bf16x8 af = __builtin_bit_cast(bf16x8, au);
        #pragma unroll
        for (int c = 0; c < 2; ++c) {
            int k = c * 16 + lr;
            short8 bv;
            if (k < NK) {
                const float* cr = &ctb[(size_t)k * NCP + kk * 32 + lg * 8];
                #pragma unroll
                for (int j = 0; j < 8; ++j) bv[j] = (short)f2bf(cr[j]);
            } else {
                #pragma unroll
                for (int j = 0; j < 8; ++j) bv[j] = 0;
            }
            acc[c] = MFMA16(af, __builtin_bit_cast(bf16x8, bv), acc[c]);
        }
    }
    #pragma unroll
    for (int c = 0; c < 2; ++c) {
        int k = c * 16 + lr;
        if (k < NK) {
            #pragma unroll
            for (int i = 0; i < 4; ++i) {
                size_t off = ((size_t)b * NK + k) * NN + n0 + lg * 4 + i;
                out[off] = cam[off] + acc[c][i];
            }
        }
    }
}

extern "C" void kernel_launch(void* const* d_in, const int* in_sizes, int n_in,
                              void* d_out, int out_size, void* d_ws, size_t ws_size,
                              hipStream_t stream) {
    const float* feat = (const float*)d_in[0];
    const float* cam  = (const float*)d_in[1];
    const float* wpr  = (const float*)d_in[2];
    const float* bpr  = (const float*)d_in[3];
    float* out = (float*)d_out;

    const size_t MB = 1024 * 1024;
    char* ws = (char*)d_ws;
    unsigned short* fp  = (unsigned short*)(ws);                 // 4 MB
    unsigned short* fpT = (unsigned short*)(ws + 4 * MB);        // 4 MB
    float* ct           = (float*)(ws + 12 * MB);                // 40 KB
    unsigned short* wb  = (unsigned short*)(ws + 12 * MB + 512 * 1024); // 128 KB
    unsigned short* po  = (unsigned short*)(ws + 13 * MB);       // 16 MB bf16 partial O
    float* mbuf         = (float*)(ws + 30 * MB);                // 256 KB
    float* lbuf         = (float*)(ws + 31 * MB);                // 256 KB

    hipMemsetAsync(ct, 0, (size_t)NB * NK * NCP * sizeof(float), stream);
    wconv_kernel<<<64, 256, 0, stream>>>(wpr, wb);
    proj_kernel<<<dim3(NN / 64, NB), 256, 0, stream>>>(feat, wb, bpr, fp, fpT);
    ct_kernel<<<NB * NK * 16, 128, 0, stream>>>(cam, fp, ct);
    attn_partial_kernel<<<dim3(NN / 128, SPLIT, NB), 256, 0, stream>>>(fp, fpT, po, mbuf, lbuf);
    aug_kernel<<<dim3(NN / 64, NB), 256, 0, stream>>>(cam, ct, po, mbuf, lbuf, out);
}